// Round 2
// baseline (921.759 us; speedup 1.0000x reference)
//
#include <hip/hip_runtime.h>
#include <cstdint>
#include <cstddef>

// SAGE-LSTM R13: R12 design with the xu-gather channel-slice fix.
// R12 bug: lanebyte = col*8 made every wave read gate channels 0..15; the
// C-init must read THIS wave's slice, channel = w*16+col -> byte w*128+col*8.
// Design (unchanged from R12):
//   8 waves x 16-channel slices of ALL 4 gates, mfma 16x16x32:
//   wreg 64 + acc 32 + cst 8 -> launch_bounds(512,4) -> 4 waves/SIMD (2x occ).
//   xu gathered global->reg directly (u32x2 gate-quad rows; 128B segments).
//   h double-buffered in LDS, XOR-swizzled (byte ^= (row&7)<<4) -> 1 barrier/step.

constexpr int IN  = 128;
constexpr int DEG = 16;

typedef short bf16x8 __attribute__((ext_vector_type(8)));
typedef float f32x4  __attribute__((ext_vector_type(4)));
typedef float f32x16 __attribute__((ext_vector_type(16)));
typedef unsigned int u32x4 __attribute__((ext_vector_type(4)));
typedef unsigned int u32x2 __attribute__((ext_vector_type(2)));

__device__ __forceinline__ float fsigmoid(float x) {
    float e = __expf(-x);
    return __builtin_amdgcn_rcpf(1.0f + e);
}
__device__ __forceinline__ float ftanh(float x) {
    float e = __expf(-2.0f * x);
    return __fmaf_rn(2.0f, __builtin_amdgcn_rcpf(1.0f + e), -1.0f);
}
__device__ __forceinline__ uint32_t pack2bf16(float a, float b) {
    uint32_t ua = __float_as_uint(a) + 0x8000u;
    uint32_t ub = __float_as_uint(b) + 0x8000u;
    return (ua >> 16) | (ub & 0xFFFF0000u);
}

// ---------- prep kernels ----------

__global__ void k_transpose_all(const float* __restrict__ s0, float* __restrict__ d0,
                                const float* __restrict__ s1, float* __restrict__ d1,
                                const float* __restrict__ s2, float* __restrict__ d2,
                                const float* __restrict__ s3, float* __restrict__ d3) {
    int i = blockIdx.x * blockDim.x + threadIdx.x;
    if (i < 16384) {
        int r = i >> 7, c = i & 127; d0[c * 128 + r] = s0[i];
    } else if (i < 32768) {
        int j = i - 16384; int r = j >> 7, c = j & 127; d1[c * 128 + r] = s1[j];
    } else if (i < 40960) {
        int j = i - 32768; int r = j >> 7, c = j & 127; d2[c * 64 + r] = s2[j];
    } else if (i < 49152) {
        int j = i - 40960; int r = j >> 7, c = j & 127; d3[c * 64 + r] = s3[j];
    }
}

__global__ void k_cast_bf16(const float* __restrict__ src, ushort* __restrict__ dst, int n) {
    int i = (blockIdx.x * blockDim.x + threadIdx.x) * 4;
    if (i + 3 < n) {
        float4 v = *(const float4*)(src + i);
        uint2 d; d.x = pack2bf16(v.x, v.y); d.y = pack2bf16(v.z, v.w);
        *(uint2*)(dst + i) = d;
    } else {
        for (int k = i; k < n; ++k)
            dst[k] = (ushort)((__float_as_uint(src[k]) + 0x8000u) >> 16);
    }
}

// Pack all 4 [512 x 128] weights into MFMA B-fragment order.
// ih (which 0,2): 32x32x16 layout (consumed by k_xu):
//   frag[(kst*16 + tile)*64 + lane]; n = tile*32+(lane&31), k = kst*16+(lane>>5)*8+j.
// hh (which 1,3): 16x16x32 layout (consumed by k_lstm_rec8):
//   frag[((g*8+w)*4+ks)*64 + lane]; jj = g*128+w*16+(lane&15), k = ks*32+(lane>>4)*8+j.
__global__ void k_pack_all(const float* __restrict__ w0, u32x4* __restrict__ f0,
                           const float* __restrict__ w1, u32x4* __restrict__ f1,
                           const float* __restrict__ w2, u32x4* __restrict__ f2,
                           const float* __restrict__ w3, u32x4* __restrict__ f3) {
    int gt = blockIdx.x * 256 + threadIdx.x;     // 0..32767
    int which = gt >> 13;
    int tid  = gt & 8191;
    const float* wsrc = (which == 0) ? w0 : (which == 1) ? w1 : (which == 2) ? w2 : w3;
    u32x4* frag = (which == 0) ? f0 : (which == 1) ? f1 : (which == 2) ? f2 : f3;
    int lane = tid & 63;
    float v[8];
    if ((which & 1) == 0) {
        // 32x32x16 B-frag (k_xu)
        int tile = (tid >> 6) & 15;
        int kst  = tid >> 10;
        int n     = tile * 32 + (lane & 31);
        int kbase = kst * 16 + (lane >> 5) * 8;
#pragma unroll
        for (int j = 0; j < 8; ++j) v[j] = wsrc[n * 128 + kbase + j];
    } else {
        // 16x16x32 B-frag (k_lstm_rec8)
        int f  = tid >> 6;            // 0..127
        int ks = f & 3;
        int w8 = (f >> 2) & 7;
        int g  = f >> 5;
        int jj    = g * 128 + w8 * 16 + (lane & 15);
        int kbase = ks * 32 + (lane >> 4) * 8;
#pragma unroll
        for (int j = 0; j < 8; ++j) v[j] = wsrc[jj * 128 + kbase + j];
    }
    u32x4 d;
    d.x = pack2bf16(v[0], v[1]);
    d.y = pack2bf16(v[2], v[3]);
    d.z = pack2bf16(v[4], v[5]);
    d.w = pack2bf16(v[6], v[7]);
    frag[tid] = d;
}

// ---------- kernel A: Xu = x @ W_ih^T + (b_ih+b_hh), gate-quad row store ----------
__global__ __launch_bounds__(256, 2) void k_xu(
    const ushort* __restrict__ x,       // [N,128] bf16
    const u32x4*  __restrict__ wih,     // 8192 B-frags (32x32 layout)
    const float*  __restrict__ b_ih,    // [512]
    const float*  __restrict__ b_hh,    // [512]
    u32x2*        __restrict__ xu,      // [Nceil][128] u32x2 (1KB rows)
    int N)
{
    __shared__ u32x4 a_buf[16][66];

    const int tid   = threadIdx.x;
    const int lane  = tid & 63;
    const int w     = tid >> 6;
    const int mrow  = lane & 31;
    const int khalf = lane >> 5;
    const int node0 = blockIdx.x * 64;

    u32x4 wreg[8][4];
#pragma unroll
    for (int kst = 0; kst < 8; ++kst)
#pragma unroll
        for (int g = 0; g < 4; ++g)
            wreg[kst][g] = wih[(kst * 16 + g * 4 + w) * 64 + lane];

    float binit[4];
#pragma unroll
    for (int g = 0; g < 4; ++g) {
        int jj = g * 128 + w * 32 + mrow;
        binit[g] = b_ih[jj] + b_hh[jj];
    }

    {
        int m_st = tid >> 2, c4 = tid & 3;
        int gn = node0 + m_st; if (gn >= N) gn = N - 1;
        const u32x4* src = (const u32x4*)(x + (size_t)gn * IN);
#pragma unroll
        for (int q = 0; q < 4; ++q) {
            int kg = q * 4 + c4;
            a_buf[kg][m_st] = src[kg];
        }
    }
    __syncthreads();

    const int coff = w * 32 + mrow;
#pragma unroll 1
    for (int Mt = 0; Mt < 2; ++Mt) {
        f32x16 acc[4];
#pragma unroll
        for (int g = 0; g < 4; ++g)
#pragma unroll
            for (int r = 0; r < 16; ++r) acc[g][r] = binit[g];

#pragma unroll
        for (int kst = 0; kst < 8; ++kst) {
            bf16x8 a = __builtin_bit_cast(bf16x8, a_buf[kst * 2 + khalf][Mt * 32 + mrow]);
#pragma unroll
            for (int g = 0; g < 4; ++g)
                acc[g] = __builtin_amdgcn_mfma_f32_32x32x16_bf16(
                    a, __builtin_bit_cast(bf16x8, wreg[kst][g]), acc[g], 0, 0, 0);
        }

#pragma unroll
        for (int r = 0; r < 16; ++r) {
            int m = Mt * 32 + (r & 3) + 8 * (r >> 2) + 4 * khalf;
            u32x2 d;
            d.x = pack2bf16(acc[0][r], acc[1][r]);
            d.y = pack2bf16(acc[2][r], acc[3][r]);
            xu[(size_t)(node0 + m) * 128 + coff] = d;
        }
    }
}

// ---------- kernel B: recurrent LSTM, 8-wave 16-col slices ----------
// wave w owns channels [w*16, w*16+16) of ALL 4 gates for 32 nodes.
// acc layout (16x16 C): node m = mt*16 + (lane>>4)*4 + q, ch = w*16 + (lane&15).
__global__ __launch_bounds__(512, 4) void k_lstm_rec8(
    const u32x2* __restrict__ xu,       // 1KB gate-quad rows
    const int*   __restrict__ nbr,      // [N,16]
    const u32x4* __restrict__ whh,      // 128 B-frags (16x16 layout)
    ushort*      __restrict__ h_out,    // [N,128] bf16
    int N)
{
    __shared__ alignas(16) ushort h_lds[2][32 * IN];   // 2 x 8KB, XOR-swizzled
    __shared__ alignas(16) int    idxs[DEG * 32];      // 2KB [t][m]

    const int tid  = threadIdx.x;
    const int lane = tid & 63;
    const int w    = tid >> 6;        // 0..7 channel block
    const int col  = lane & 15;
    const int l4   = lane >> 4;       // 0..3
    const int node0 = blockIdx.x * 32;

    {   // idxs[t*32+m], one per thread
        int m = tid & 31, t = tid >> 5;
        int gn = node0 + m; if (gn >= N) gn = N - 1;
        idxs[t * 32 + m] = nbr[gn * DEG + t];
    }
    // zero h(-1) buffer (parity: step t writes buf[t&1], reads buf[(t+1)&1])
    ((u32x4*)h_lds[1])[tid] = u32x4{0u, 0u, 0u, 0u};

    // W_hh fragments: 64 VGPRs
    u32x4 wreg[4][4];
#pragma unroll
    for (int g = 0; g < 4; ++g)
#pragma unroll
        for (int ks = 0; ks < 4; ++ks)
            wreg[g][ks] = whh[((g * 8 + w) * 4 + ks) * 64 + lane];

    float cst[8];
#pragma unroll
    for (int r = 0; r < 8; ++r) cst[r] = 0.0f;

    const char* xu_c = (const char*)xu;
    // R13 FIX: this wave's gate-quad slice is channel w*16+col -> byte w*128+col*8
    const uint32_t lanebyte = (uint32_t)(w * 128 + col * 8);
    const uint32_t cb = (uint32_t)(w * 32 + col * 2);   // h-write ch byte
    const uint32_t aswz = ((uint32_t)(col & 7)) << 4;   // A-read row swizzle

    __syncthreads();

#pragma unroll 1
    for (int t = 0; t < DEG; ++t) {
        const char* hr = (const char*)h_lds[(t + 1) & 1];
        char*       hw = (char*)h_lds[t & 1];

        // ---- gather 8 xu gate-quads (global->reg; 128B segments, L2/L3 served)
        const int4 i0 = *(const int4*)&idxs[t * 32 + l4 * 4];
        const int4 i1 = *(const int4*)&idxs[t * 32 + 16 + l4 * 4];
        u32x2 v[8];
        v[0] = *(const u32x2*)(xu_c + (size_t)((uint32_t)i0.x * 1024u + lanebyte));
        v[1] = *(const u32x2*)(xu_c + (size_t)((uint32_t)i0.y * 1024u + lanebyte));
        v[2] = *(const u32x2*)(xu_c + (size_t)((uint32_t)i0.z * 1024u + lanebyte));
        v[3] = *(const u32x2*)(xu_c + (size_t)((uint32_t)i0.w * 1024u + lanebyte));
        v[4] = *(const u32x2*)(xu_c + (size_t)((uint32_t)i1.x * 1024u + lanebyte));
        v[5] = *(const u32x2*)(xu_c + (size_t)((uint32_t)i1.y * 1024u + lanebyte));
        v[6] = *(const u32x2*)(xu_c + (size_t)((uint32_t)i1.z * 1024u + lanebyte));
        v[7] = *(const u32x2*)(xu_c + (size_t)((uint32_t)i1.w * 1024u + lanebyte));

        // ---- unpack as MFMA C-init (gate order matches k_xu's pack)
        f32x4 acc[4][2];
#pragma unroll
        for (int mt = 0; mt < 2; ++mt)
#pragma unroll
            for (int q = 0; q < 4; ++q) {
                u32x2 p = v[mt * 4 + q];
                acc[0][mt][q] = __uint_as_float(p.x << 16);
                acc[1][mt][q] = __uint_as_float(p.x & 0xFFFF0000u);
                acc[2][mt][q] = __uint_as_float(p.y << 16);
                acc[3][mt][q] = __uint_as_float(p.y & 0xFFFF0000u);
            }

        // ---- MFMA: A = h(t-1) from swizzled LDS, B = wreg
#pragma unroll
        for (int ks = 0; ks < 4; ++ks) {
            const uint32_t ab = ((uint32_t)(ks * 64 + l4 * 16)) ^ aswz;
            bf16x8 a0 = *(const bf16x8*)(hr + col * 256 + ab);
            bf16x8 a1 = *(const bf16x8*)(hr + 4096 + col * 256 + ab);
#pragma unroll
            for (int g = 0; g < 4; ++g) {
                acc[g][0] = __builtin_amdgcn_mfma_f32_16x16x32_bf16(
                    a0, __builtin_bit_cast(bf16x8, wreg[g][ks]), acc[g][0], 0, 0, 0);
                acc[g][1] = __builtin_amdgcn_mfma_f32_16x16x32_bf16(
                    a1, __builtin_bit_cast(bf16x8, wreg[g][ks]), acc[g][1], 0, 0, 0);
            }
        }

        // ---- cell update + swizzled bf16 h write (registers -> LDS)
#pragma unroll
        for (int mt = 0; mt < 2; ++mt)
#pragma unroll
            for (int q = 0; q < 4; ++q) {
                int r = mt * 4 + q;
                float iv = fsigmoid(acc[0][mt][q]);
                float fv = fsigmoid(acc[1][mt][q]);
                float gv = ftanh(acc[2][mt][q]);
                float ov = fsigmoid(acc[3][mt][q]);
                float cv = __fmaf_rn(fv, cst[r], iv * gv);
                cst[r] = cv;
                float hv = ov * ftanh(cv);
                int m = mt * 16 + l4 * 4 + q;
                uint32_t hb = (__float_as_uint(hv) + 0x8000u) >> 16;
                *(ushort*)(hw + m * 256 + (cb ^ (((uint32_t)(m & 7)) << 4))) = (ushort)hb;
            }

        __syncthreads();   // single barrier/step: h(t) visible, WAR safe via dbuf
    }

    // ---- writeout: h(15) lives in h_lds[1]
    {
        int m = tid >> 4, c16 = tid & 15;
        int gn = node0 + m;
        if (gn < N) {
            u32x4 val = *(const u32x4*)((const char*)h_lds[1] + m * 256 +
                                        (((uint32_t)(c16 * 16)) ^ (((uint32_t)(m & 7)) << 4)));
            *(u32x4*)(h_out + (size_t)gn * IN + c16 * 8) = val;
        }
    }
}

// ---------- output linear (fp32 math, bf16 inputs) ----------

template <int NOUT, int ACT, typename OutT>
__global__ __launch_bounds__(256) void k_out_linear(
    const ushort* __restrict__ x, const ushort* __restrict__ h,
    const float* __restrict__ wTs, const float* __restrict__ wTn,
    const float* __restrict__ bias, OutT* __restrict__ out, int N)
{
    constexpr int NPS = 32 / (256 / NOUT);
    __shared__ alignas(16) float x_lds[32][IN];
    __shared__ alignas(16) float h_lds[32][IN];

    const int tid  = threadIdx.x;
    const int j    = tid % NOUT;
    const int slot = tid / NOUT;
    const int node0 = blockIdx.x * 32;

    for (int i = tid; i < 32 * (IN / 8); i += 256) {
        int n = i >> 4, u4 = i & 15;
        int gn = node0 + n; if (gn >= N) gn = N - 1;
        u32x4 xv = *(const u32x4*)(x + (size_t)gn * IN + u4 * 8);
        u32x4 hv = *(const u32x4*)(h + (size_t)gn * IN + u4 * 8);
        float* xd = &x_lds[n][u4 * 8];
        float* hd = &h_lds[n][u4 * 8];
        xd[0] = __uint_as_float(xv.x << 16); xd[1] = __uint_as_float(xv.x & 0xFFFF0000u);
        xd[2] = __uint_as_float(xv.y << 16); xd[3] = __uint_as_float(xv.y & 0xFFFF0000u);
        xd[4] = __uint_as_float(xv.z << 16); xd[5] = __uint_as_float(xv.z & 0xFFFF0000u);
        xd[6] = __uint_as_float(xv.w << 16); xd[7] = __uint_as_float(xv.w & 0xFFFF0000u);
        hd[0] = __uint_as_float(hv.x << 16); hd[1] = __uint_as_float(hv.x & 0xFFFF0000u);
        hd[2] = __uint_as_float(hv.y << 16); hd[3] = __uint_as_float(hv.y & 0xFFFF0000u);
        hd[4] = __uint_as_float(hv.z << 16); hd[5] = __uint_as_float(hv.z & 0xFFFF0000u);
        hd[6] = __uint_as_float(hv.w << 16); hd[7] = __uint_as_float(hv.w & 0xFFFF0000u);
    }
    __syncthreads();

    float acc[NPS];
    const float bj = bias[j];
#pragma unroll
    for (int n = 0; n < NPS; ++n) acc[n] = bj;

#pragma unroll 2
    for (int k = 0; k < IN; ++k) {
        const float ws = wTs[k * NOUT + j];
        const float wn = wTn[k * NOUT + j];
#pragma unroll
        for (int n = 0; n < NPS; ++n) {
            acc[n] = __fmaf_rn(x_lds[slot * NPS + n][k], ws,
                     __fmaf_rn(h_lds[slot * NPS + n][k], wn, acc[n]));
        }
    }

#pragma unroll
    for (int n = 0; n < NPS; ++n) {
        int gn = node0 + slot * NPS + n;
        if (gn < N) {
            float v = acc[n];
            v = (ACT == 0) ? fmaxf(v, 0.0f) : fsigmoid(v);
            if constexpr (sizeof(OutT) == 2)
                out[(size_t)gn * NOUT + j] = (OutT)((__float_as_uint(v) + 0x8000u) >> 16);
            else
                out[(size_t)gn * NOUT + j] = v;
        }
    }
}

extern "C" void kernel_launch(void* const* d_in, const int* in_sizes, int n_in,
                              void* d_out, int out_size, void* d_ws, size_t ws_size,
                              hipStream_t stream)
{
    const float* feats    = (const float*)d_in[0];
    const int*   nbr      = (const int*)  d_in[1];
    const float* w_ih1    = (const float*)d_in[2];
    const float* w_hh1    = (const float*)d_in[3];
    const float* b_ih1    = (const float*)d_in[4];
    const float* b_hh1    = (const float*)d_in[5];
    const float* w_self1  = (const float*)d_in[6];
    const float* w_neigh1 = (const float*)d_in[7];
    const float* b1       = (const float*)d_in[8];
    const float* w_ih2    = (const float*)d_in[9];
    const float* w_hh2    = (const float*)d_in[10];
    const float* b_ih2    = (const float*)d_in[11];
    const float* b_hh2    = (const float*)d_in[12];
    const float* w_self2  = (const float*)d_in[13];
    const float* w_neigh2 = (const float*)d_in[14];
    const float* b2       = (const float*)d_in[15];
    float* out = (float*)d_out;

    const int N = in_sizes[0] / IN;   // 50000
    const long long Nceil = (N + 63) & ~63LL;

    char* ws = (char*)d_ws;
    size_t off = 0;
    auto alloc = [&](size_t bytes) -> void* {
        void* p = (void*)(ws + off);
        off += (bytes + 255) & ~(size_t)255;
        return p;
    };
    u32x4*  wfrag_ih1 = (u32x4*)alloc(8192 * 16);
    u32x4*  wfrag_hh1 = (u32x4*)alloc(8192 * 16);
    u32x4*  wfrag_ih2 = (u32x4*)alloc(8192 * 16);
    u32x4*  wfrag_hh2 = (u32x4*)alloc(8192 * 16);
    float*  wT_self1  = (float*)alloc(128 * 128 * 4);
    float*  wT_neigh1 = (float*)alloc(128 * 128 * 4);
    float*  wT_self2  = (float*)alloc(64 * 128 * 4);
    float*  wT_neigh2 = (float*)alloc(64 * 128 * 4);
    ushort* feats_bf  = (ushort*)alloc((size_t)N * 128 * 2);
    ushort* h_buf     = (ushort*)alloc((size_t)N * 128 * 2);
    ushort* out1      = (ushort*)alloc((size_t)N * 128 * 2);
    u32x2*  xu_buf    = (u32x2*)alloc((size_t)Nceil * 128 * 8);   // 51.25MB

    // prep (fused)
    k_pack_all<<<dim3(128), dim3(256), 0, stream>>>(w_ih1, wfrag_ih1, w_hh1, wfrag_hh1,
                                                    w_ih2, wfrag_ih2, w_hh2, wfrag_hh2);
    k_transpose_all<<<dim3(192), dim3(256), 0, stream>>>(w_self1, wT_self1, w_neigh1, wT_neigh1,
                                                         w_self2, wT_self2, w_neigh2, wT_neigh2);
    k_cast_bf16<<<dim3((N * 128 / 4 + 255) / 256), dim3(256), 0, stream>>>(feats, feats_bf, N * 128);

    const int nblk64 = (int)(Nceil / 64);
    const int nblk32 = (N + 31) / 32;

    // layer 1
    k_xu<<<dim3(nblk64), dim3(256), 0, stream>>>(feats_bf, wfrag_ih1, b_ih1, b_hh1, xu_buf, N);
    k_lstm_rec8<<<dim3(nblk32), dim3(512), 0, stream>>>(xu_buf, nbr, wfrag_hh1, h_buf, N);
    k_out_linear<128, 0, ushort><<<dim3(nblk32), dim3(256), 0, stream>>>(feats_bf, h_buf, wT_self1, wT_neigh1, b1, out1, N);

    // layer 2
    k_xu<<<dim3(nblk64), dim3(256), 0, stream>>>(out1, wfrag_ih2, b_ih2, b_hh2, xu_buf, N);
    k_lstm_rec8<<<dim3(nblk32), dim3(512), 0, stream>>>(xu_buf, nbr, wfrag_hh2, h_buf, N);
    k_out_linear<64, 1, float><<<dim3(nblk32), dim3(256), 0, stream>>>(out1, h_buf, wT_self2, wT_neigh2, b2, out, N);
}